// Round 1
// baseline (65.500 us; speedup 1.0000x reference)
//
#include <hip/hip_runtime.h>

// Izhikevich constants (float32, matching the reference)
#define IZH_K     0.4471817006977834f
#define IZH_A     0.0032799410036917333f
#define IZH_B     24.478421990208606f
#define IZH_VMIN  -66.46563513097735f
#define IZH_D     50.0f
#define IZH_C     38.0f
#define IZH_VR    -77.40291336465064f
#define IZH_VT    -44.90054428048817f
#define IZH_VPEAK 15.489726771001997f

__device__ __forceinline__ void izh_step(float v, float u, float I,
                                         float h, float h_over_C,
                                         float& vo, float& uo) {
    // subthreshold integration (v first, then u with the NEW v)
    float dv    = IZH_K * (v - IZH_VR) * (v - IZH_VT) - u + I;
    float v_int = v + dv * h_over_C;
    float u_int = u + h * (IZH_A * (IZH_B * (v_int - IZH_VR) - u));
    bool  spike = v >= IZH_VPEAK;
    vo = spike ? IZH_VMIN    : v_int;
    uo = spike ? (u + IZH_D) : u_int;
}

__global__ void __launch_bounds__(256)
izhikevich_kernel(const float* __restrict__ v,
                  const float* __restrict__ u,
                  const float* __restrict__ I,
                  const float* __restrict__ hptr,
                  float* __restrict__ vout,
                  float* __restrict__ uout,
                  int n) {
    const float h = hptr[0];          // uniform scalar, L2-broadcast
    const float h_over_C = h / IZH_C;

    const int n4     = n >> 2;        // float4 count
    const int tid    = blockIdx.x * blockDim.x + threadIdx.x;
    const int stride = gridDim.x * blockDim.x;

    const float4* v4 = reinterpret_cast<const float4*>(v);
    const float4* u4 = reinterpret_cast<const float4*>(u);
    const float4* I4 = reinterpret_cast<const float4*>(I);
    float4* vo4 = reinterpret_cast<float4*>(vout);
    float4* uo4 = reinterpret_cast<float4*>(uout);

    for (int i = tid; i < n4; i += stride) {
        float4 vv = v4[i];
        float4 uu = u4[i];
        float4 ii = I4[i];
        float4 vo, uo;
        izh_step(vv.x, uu.x, ii.x, h, h_over_C, vo.x, uo.x);
        izh_step(vv.y, uu.y, ii.y, h, h_over_C, vo.y, uo.y);
        izh_step(vv.z, uu.z, ii.z, h, h_over_C, vo.z, uo.z);
        izh_step(vv.w, uu.w, ii.w, h, h_over_C, vo.w, uo.w);
        vo4[i] = vo;
        uo4[i] = uo;
    }

    // scalar tail (n not divisible by 4) — no-op for N = 2^24
    for (int i = (n4 << 2) + tid; i < n; i += stride) {
        float vo, uo;
        izh_step(v[i], u[i], I[i], h, h_over_C, vo, uo);
        vout[i] = vo;
        uout[i] = uo;
    }
}

extern "C" void kernel_launch(void* const* d_in, const int* in_sizes, int n_in,
                              void* d_out, int out_size, void* d_ws, size_t ws_size,
                              hipStream_t stream) {
    const float* v    = (const float*)d_in[0];
    const float* u    = (const float*)d_in[1];
    const float* I    = (const float*)d_in[2];
    // d_in[3] = mem — unused by the reference; never loaded.
    const float* hptr = (const float*)d_in[4];

    const int n = in_sizes[0];
    float* vout = (float*)d_out;        // first N floats
    float* uout = (float*)d_out + n;    // next N floats

    const int block = 256;
    int grid = (n / 4 + block - 1) / block;
    if (grid > 2048) grid = 2048;       // grid-stride cap (G11)

    izhikevich_kernel<<<grid, block, 0, stream>>>(v, u, I, hptr, vout, uout, n);
}

// Round 4
// 56.964 us; speedup vs baseline: 1.1499x; 1.1499x over previous
//
#include <hip/hip_runtime.h>

// Izhikevich constants (float32, matching the reference)
#define IZH_K     0.4471817006977834f
#define IZH_A     0.0032799410036917333f
#define IZH_B     24.478421990208606f
#define IZH_VMIN  -66.46563513097735f
#define IZH_D     50.0f
#define IZH_C     38.0f
#define IZH_VR    -77.40291336465064f
#define IZH_VT    -44.90054428048817f
#define IZH_VPEAK 15.489726771001997f

// clang-native vector: accepted by __builtin_nontemporal_store (HIP's float4
// struct is not), still one dwordx4 per access.
typedef float fx4 __attribute__((ext_vector_type(4)));

__device__ __forceinline__ void izh_step(float v, float u, float I,
                                         float h, float h_over_C,
                                         float& vo, float& uo) {
    // subthreshold integration (v first, then u with the NEW v)
    float dv    = IZH_K * (v - IZH_VR) * (v - IZH_VT) - u + I;
    float v_int = v + dv * h_over_C;
    float u_int = u + h * (IZH_A * (IZH_B * (v_int - IZH_VR) - u));
    bool  spike = v >= IZH_VPEAK;
    vo = spike ? IZH_VMIN    : v_int;
    uo = spike ? (u + IZH_D) : u_int;
}

__global__ void __launch_bounds__(256)
izhikevich_kernel(const float* __restrict__ v,
                  const float* __restrict__ u,
                  const float* __restrict__ I,
                  const float* __restrict__ hptr,
                  float* __restrict__ vout,
                  float* __restrict__ uout,
                  int n) {
    const float h = hptr[0];          // uniform scalar, L2-broadcast
    const float h_over_C = h / IZH_C;

    const int n4     = n >> 2;        // float4 count
    const int tid    = blockIdx.x * blockDim.x + threadIdx.x;
    const int stride = gridDim.x * blockDim.x;

    const fx4* v4 = reinterpret_cast<const fx4*>(v);
    const fx4* u4 = reinterpret_cast<const fx4*>(u);
    const fx4* I4 = reinterpret_cast<const fx4*>(I);
    fx4* vo4 = reinterpret_cast<fx4*>(vout);
    fx4* uo4 = reinterpret_cast<fx4*>(uout);

    for (int i = tid; i < n4; i += stride) {
        fx4 vv = v4[i];   // cached loads — keep L3 reuse across replays
        fx4 uu = u4[i];
        fx4 ii = I4[i];
        fx4 vo, uo;
        #pragma unroll
        for (int k = 0; k < 4; ++k) {
            float vok, uok;  // ext_vector elems can't bind to float& — use locals
            izh_step(vv[k], uu[k], ii[k], h, h_over_C, vok, uok);
            vo[k] = vok;
            uo[k] = uok;
        }
        // write-once, never re-read: nontemporal -> don't pollute L2/L3,
        // leave the Infinity Cache to the (re-read) inputs.
        __builtin_nontemporal_store(vo, &vo4[i]);
        __builtin_nontemporal_store(uo, &uo4[i]);
    }

    // scalar tail (n not divisible by 4) — no-op for N = 2^24
    for (int i = (n4 << 2) + tid; i < n; i += stride) {
        float vo, uo;
        izh_step(v[i], u[i], I[i], h, h_over_C, vo, uo);
        __builtin_nontemporal_store(vo, &vout[i]);
        __builtin_nontemporal_store(uo, &uout[i]);
    }
}

extern "C" void kernel_launch(void* const* d_in, const int* in_sizes, int n_in,
                              void* d_out, int out_size, void* d_ws, size_t ws_size,
                              hipStream_t stream) {
    const float* v    = (const float*)d_in[0];
    const float* u    = (const float*)d_in[1];
    const float* I    = (const float*)d_in[2];
    // d_in[3] = mem — unused by the reference; never loaded.
    const float* hptr = (const float*)d_in[4];

    const int n = in_sizes[0];
    float* vout = (float*)d_out;        // first N floats
    float* uout = (float*)d_out + n;    // next N floats

    const int block = 256;
    int grid = (n / 4 + block - 1) / block;
    if (grid > 2048) grid = 2048;       // 2048 blk × 4 waves = 8192 waves = full residency

    izhikevich_kernel<<<grid, block, 0, stream>>>(v, u, I, hptr, vout, uout, n);
}

// Round 5
// 56.172 us; speedup vs baseline: 1.1661x; 1.0141x over previous
//
#include <hip/hip_runtime.h>

// Izhikevich constants (float32, matching the reference)
#define IZH_K     0.4471817006977834f
#define IZH_A     0.0032799410036917333f
#define IZH_B     24.478421990208606f
#define IZH_VMIN  -66.46563513097735f
#define IZH_D     50.0f
#define IZH_C     38.0f
#define IZH_VR    -77.40291336465064f
#define IZH_VT    -44.90054428048817f
#define IZH_VPEAK 15.489726771001997f

// clang-native vector: accepted by __builtin_nontemporal_store (HIP's float4
// struct is not), still one dwordx4 per access.
typedef float fx4 __attribute__((ext_vector_type(4)));

__device__ __forceinline__ void izh_step(float v, float u, float I,
                                         float h, float h_over_C,
                                         float& vo, float& uo) {
    // subthreshold integration (v first, then u with the NEW v)
    float dv    = IZH_K * (v - IZH_VR) * (v - IZH_VT) - u + I;
    float v_int = v + dv * h_over_C;
    float u_int = u + h * (IZH_A * (IZH_B * (v_int - IZH_VR) - u));
    bool  spike = v >= IZH_VPEAK;
    vo = spike ? IZH_VMIN    : v_int;
    uo = spike ? (u + IZH_D) : u_int;
}

__device__ __forceinline__ fx4 izh_v4(fx4 vv, fx4 uu, fx4 ii,
                                      float h, float h_over_C, fx4& uo) {
    fx4 vo;
    #pragma unroll
    for (int k = 0; k < 4; ++k) {
        float vok, uok;  // ext_vector elems can't bind to float& — use locals
        izh_step(vv[k], uu[k], ii[k], h, h_over_C, vok, uok);
        vo[k] = vok;
        uo[k] = uok;
    }
    return vo;
}

__global__ void __launch_bounds__(256)
izhikevich_kernel(const float* __restrict__ v,
                  const float* __restrict__ u,
                  const float* __restrict__ I,
                  const float* __restrict__ hptr,
                  float* __restrict__ vout,
                  float* __restrict__ uout,
                  int n) {
    const float h = hptr[0];          // uniform scalar, L2-broadcast
    const float h_over_C = h / IZH_C;

    const int n4     = n >> 2;        // fx4 count
    const int tid    = blockIdx.x * blockDim.x + threadIdx.x;
    const int total  = gridDim.x * blockDim.x;

    const fx4* v4 = reinterpret_cast<const fx4*>(v);
    const fx4* u4 = reinterpret_cast<const fx4*>(u);
    const fx4* I4 = reinterpret_cast<const fx4*>(I);
    fx4* vo4 = reinterpret_cast<fx4*>(vout);
    fx4* uo4 = reinterpret_cast<fx4*>(uout);

    // 2x-unrolled grid-stride: 6 independent dwordx4 loads in flight per
    // iteration (MLP), both groups fully coalesced (i and i+total).
    int i = tid;
    for (; i + total < n4; i += 2 * total) {
        const int j = i + total;
        fx4 vv1 = v4[i];  fx4 vv2 = v4[j];
        fx4 uu1 = u4[i];  fx4 uu2 = u4[j];
        fx4 ii1 = I4[i];  fx4 ii2 = I4[j];
        fx4 uo1, uo2;
        fx4 vo1 = izh_v4(vv1, uu1, ii1, h, h_over_C, uo1);
        fx4 vo2 = izh_v4(vv2, uu2, ii2, h, h_over_C, uo2);
        // write-once, never re-read: nt stores skip L2 write-allocate so the
        // 128 MiB of output doesn't evict inputs from L2 (round-4 finding).
        __builtin_nontemporal_store(vo1, &vo4[i]);
        __builtin_nontemporal_store(uo1, &uo4[i]);
        __builtin_nontemporal_store(vo2, &vo4[j]);
        __builtin_nontemporal_store(uo2, &uo4[j]);
    }
    // odd remaining fx4 group (when n4/total is odd)
    for (; i < n4; i += total) {
        fx4 vv = v4[i], uu = u4[i], ii = I4[i];
        fx4 uo;
        fx4 vo = izh_v4(vv, uu, ii, h, h_over_C, uo);
        __builtin_nontemporal_store(vo, &vo4[i]);
        __builtin_nontemporal_store(uo, &uo4[i]);
    }

    // scalar tail (n not divisible by 4) — no-op for N = 2^24
    for (int s = (n4 << 2) + tid; s < n; s += total) {
        float vo, uo;
        izh_step(v[s], u[s], I[s], h, h_over_C, vo, uo);
        __builtin_nontemporal_store(vo, &vout[s]);
        __builtin_nontemporal_store(uo, &uout[s]);
    }
}

extern "C" void kernel_launch(void* const* d_in, const int* in_sizes, int n_in,
                              void* d_out, int out_size, void* d_ws, size_t ws_size,
                              hipStream_t stream) {
    const float* v    = (const float*)d_in[0];
    const float* u    = (const float*)d_in[1];
    const float* I    = (const float*)d_in[2];
    // d_in[3] = mem — unused by the reference; never loaded.
    const float* hptr = (const float*)d_in[4];

    const int n = in_sizes[0];
    float* vout = (float*)d_out;        // first N floats
    float* uout = (float*)d_out + n;    // next N floats

    const int block = 256;
    int grid = (n / 4 + block - 1) / block;
    if (grid > 2048) grid = 2048;       // 2048 blk × 4 waves = 8192 waves = full residency

    izhikevich_kernel<<<grid, block, 0, stream>>>(v, u, I, hptr, vout, uout, n);
}